// Round 11
// baseline (285.343 us; speedup 1.0000x reference)
//
#include <hip/hip_runtime.h>

#define HALF 128
#define NMAT 16384   // 128*128
#define NTOK 131072  // 32*4096

typedef float f4 __attribute__((ext_vector_type(4)));

// N[r][c] for N = I + A/2, A = tril(X) - tril(X)^T  (identical math/order to
// the verified kernels' reg-init).
__device__ __forceinline__ float nval(const float* __restrict__ X, int r, int c) {
    int mx = r > c ? r : c;
    int mn = r ^ c ^ mx;
    float x = X[mx * HALF + mn];
    return (r == c) ? 1.0f : (r > c ? 0.5f * x : -0.5f * x);
}

// ---------------------------------------------------------------------------
// K1 (round-11): ONE persistent 16-block dispatch; the 7 inter-step dispatch
// boundaries of round 9 (~4.7us each) become device-scope software barriers
// (Guideline-16 pattern: release threadfence -> atomicAdd arrive -> spin on
// device-scope atomic -> acquire threadfence; handles cross-XCD L2
// non-coherence).  16 blocks x 256 thr trivially co-resident.  Per-step body
// is VERBATIM round-9 k1_step (no added serial work -- round-10 lesson).
// Barrier counter zeroed by hipMemsetAsync (workspace is re-poisoned each
// iteration).  Bit-identical output.
// ---------------------------------------------------------------------------
__device__ __forceinline__ void gbarrier(int* __restrict__ bar, int target, int t) {
    __threadfence();                       // release: make Wout writes visible
    __syncthreads();
    if (t == 0) {
        atomicAdd(bar, 1);
        while (atomicAdd(bar, 0) < target) __builtin_amdgcn_s_sleep(2);
    }
    __syncthreads();
    __threadfence();                       // acquire: invalidate stale cache
}

__global__ __launch_bounds__(256) void k1_persist(const float* __restrict__ prim,
                                                  float* __restrict__ W0,
                                                  float* __restrict__ W1,
                                                  float* __restrict__ QT,
                                                  int* __restrict__ bar) {
    __shared__ __align__(16) float Rs[16][132];   // R = pre-step W[K,:]
    __shared__ float Dc[16][17];                  // Dc[a][b] = Dinv[b][a]
    __shared__ __align__(16) float RBs[16][132];  // RB[m][c] (Dinv in panel cols)
    __shared__ float Cs[16][17];                  // own-rows C-slice

    const int blk = blockIdx.x;
    const int b   = blk >> 3;            // matrix
    const int rg  = blk & 7;             // row-group: rows r0..r0+15
    const int r0  = rg << 4;
    const int t   = threadIdx.x;
    const float* __restrict__ X = prim + b * NMAT;

    for (int S = 0; S < 8; ++S) {
        const bool FIRST = (S == 0);
        const bool LAST  = (S == 7);
        const int  k0    = S << 4;
        // ping-pong: out(s) = (s&1)?W1:W0 (s<7); in(s) = out(s-1); step7 -> QT
        const float* __restrict__ Wi =
            (FIRST ? W0 : (((S - 1) & 1) ? W1 : W0)) + b * NMAT;  // unused if FIRST
        float* __restrict__ Wo =
            (LAST ? QT : ((S & 1) ? W1 : W0)) + b * NMAT;

        {   // stage R: row j = t>>4, cols 8*(t&15)..+8   (verbatim round 9)
            const int j  = t >> 4;
            const int c0 = (t & 15) << 3;
            if (FIRST) {
                #pragma unroll
                for (int u = 0; u < 8; ++u) Rs[j][c0 + u] = nval(X, k0 + j, c0 + u);
            } else {
                float4 a  = *(const float4*)&Wi[(k0 + j) * HALF + c0];
                float4 b2 = *(const float4*)&Wi[(k0 + j) * HALF + c0 + 4];
                *(float4*)&Rs[j][c0]     = a;
                *(float4*)&Rs[j][c0 + 4] = b2;
            }
        }
        {   // stage C-slice: rows r0..r0+16, cols k0..k0+16 (pre-step values)
            const int rr = t >> 4, m = t & 15;
            Cs[rr][m] = FIRST ? nval(X, r0 + rr, k0 + m)
                              : Wi[(r0 + rr) * HALF + k0 + m];
        }
        __syncthreads();

        if (t < 64) {   // wave 0: shuffle-GJ invert D (verbatim)
            const int cp = t & 15, q4 = t >> 4;
            float dd[4];
            #pragma unroll
            for (int i = 0; i < 4; ++i) dd[i] = Rs[q4 * 4 + i][k0 + cp];
            #pragma unroll
            for (int k = 0; k < 16; ++k) {
                float cv[4];
                #pragma unroll
                for (int i = 0; i < 4; ++i) cv[i] = __shfl(dd[i], (q4 << 4) | k);
                float rv   = __shfl(dd[k & 3], ((k >> 2) << 4) | cp);
                float dkk  = __shfl(rv, k);
                float dinv = 1.0f / dkk;
                float sv   = rv * dinv;
                bool  own  = (cp == k);
                float rf   = own ? dinv : sv;
                #pragma unroll
                for (int i = 0; i < 4; ++i)
                    dd[i] = own ? (-dd[i] * dinv) : fmaf(-cv[i], sv, dd[i]);
                dd[k & 3] = (q4 == (k >> 2)) ? rf : dd[k & 3];
            }
            #pragma unroll
            for (int i = 0; i < 4; ++i) Dc[cp][q4 * 4 + i] = dd[i];
        }
        __syncthreads();

        {   // RB[m][c] in LDS: m = t>>4, cols 8*(t&15)..+8; j ascending
            const int m  = t >> 4;
            const int c0 = (t & 15) << 3;
            if (c0 == k0 || c0 == k0 + 8) {
                #pragma unroll
                for (int u = 0; u < 8; ++u) RBs[m][c0 + u] = Dc[c0 + u - k0][m];
            } else {
                float acc[8] = {0.f,0.f,0.f,0.f,0.f,0.f,0.f,0.f};
                #pragma unroll
                for (int j = 0; j < 16; ++j) {
                    float dj = Dc[j][m];
                    #pragma unroll
                    for (int u = 0; u < 8; ++u)
                        acc[u] = fmaf(dj, Rs[j][c0 + u], acc[u]);
                }
                *(float4*)&RBs[m][c0]     = make_float4(acc[0], acc[1], acc[2], acc[3]);
                *(float4*)&RBs[m][c0 + 4] = make_float4(acc[4], acc[5], acc[6], acc[7]);
            }
        }
        __syncthreads();

        {   // update own 16 rows, write to Wout (disjoint -> race-free)
            const int rr = t >> 4;
            const int r  = r0 + rr;
            const int c0 = (t & 15) << 3;
            float w[8];

            if (rg == S) {                       // rows K: W[K,:] = RB
                #pragma unroll
                for (int u = 0; u < 8; ++u) w[u] = RBs[rr][c0 + u];
            } else {
                const bool pan = (c0 == k0) || (c0 == k0 + 8);
                if (pan) {
                    #pragma unroll
                    for (int u = 0; u < 8; ++u) w[u] = 0.0f;
                } else if (FIRST) {
                    #pragma unroll
                    for (int u = 0; u < 8; ++u) w[u] = nval(X, r, c0 + u);
                } else {
                    float4 a  = *(const float4*)&Wi[r * HALF + c0];
                    float4 b2 = *(const float4*)&Wi[r * HALF + c0 + 4];
                    w[0]=a.x; w[1]=a.y; w[2]=a.z; w[3]=a.w;
                    w[4]=b2.x; w[5]=b2.y; w[6]=b2.z; w[7]=b2.w;
                }
                #pragma unroll
                for (int m = 0; m < 16; ++m) {   // m ascending (verbatim)
                    float cm = Cs[rr][m];
                    #pragma unroll
                    for (int u = 0; u < 8; ++u)
                        w[u] = fmaf(-cm, RBs[m][c0 + u], w[u]);
                }
            }

            if (LAST) {
                #pragma unroll
                for (int u = 0; u < 8; ++u)
                    w[u] = 2.0f * w[u] - ((r == c0 + u) ? 1.0f : 0.0f);
            }
            *(float4*)&Wo[r * HALF + c0]     = make_float4(w[0], w[1], w[2], w[3]);
            *(float4*)&Wo[r * HALF + c0 + 4] = make_float4(w[4], w[5], w[6], w[7]);
        }

        if (!LAST) gbarrier(bar, 16 * (S + 1), t);   // all writes of step S done
        // LDS reuse next step is guarded by gbarrier's internal syncthreads.
    }
}

// ---------------------------------------------------------------------------
// K2a: rows [0,256) from identity, steps d=0..6.  ROUND-2 VERIFIED FORM.
// ---------------------------------------------------------------------------
__global__ __launch_bounds__(256) void path_base(const float* __restrict__ QT,
                                                 const float* __restrict__ ident,
                                                 float* __restrict__ P) {
    __shared__ __align__(16) float vs[2][4][HALF];
    const int t    = threadIdx.x;
    const int rg   = t >> 6;                 // row in block (0..3), one wave each
    const int jj   = (t & 63) << 1;          // 2-col chunk
    const int v    = (blockIdx.x << 2) + rg;
    const int vmax = (blockIdx.x << 2) + 3;

    float2 cv = *(const float2*)&ident[jj];
    *(float2*)&vs[0][rg][jj] = cv;
    __syncthreads();

    int cur = 0;
    for (int d = 0; d < 8; ++d) {
        if ((vmax >> (d + 1)) == 0) break;           // block-uniform
        const bool valid = (v >> (d + 1)) > 0;
        const float* __restrict__ Qm = QT + (((v >> d) & 1) ? NMAT : 0);
        float2 acc = make_float2(0.f, 0.f);
        #pragma unroll 4
        for (int cc = 0; cc < 128; cc += 4) {
            float4 v4 = *(const float4*)&vs[cur][rg][cc];
            float2 q0 = *(const float2*)&Qm[(cc+0)*HALF + jj];
            float2 q1 = *(const float2*)&Qm[(cc+1)*HALF + jj];
            float2 q2 = *(const float2*)&Qm[(cc+2)*HALF + jj];
            float2 q3 = *(const float2*)&Qm[(cc+3)*HALF + jj];
            acc.x = fmaf(v4.x,q0.x, fmaf(v4.y,q1.x, fmaf(v4.z,q2.x, fmaf(v4.w,q3.x, acc.x))));
            acc.y = fmaf(v4.x,q0.y, fmaf(v4.y,q1.y, fmaf(v4.z,q2.y, fmaf(v4.w,q3.y, acc.y))));
        }
        if (valid) cv = acc;
        *(float2*)&vs[cur ^ 1][rg][jj] = cv;
        __syncthreads();
        cur ^= 1;
    }
    *(float2*)&P[v * HALF + jj] = cv;
}

// ---------------------------------------------------------------------------
// K2b: rows [256,4096), k-grouped, column-parallel, 256 threads.
// ROUND-4 VERIFIED FORM.
// ---------------------------------------------------------------------------
__global__ __launch_bounds__(256) void path_upper(const float* __restrict__ QT,
                                                  float* __restrict__ P) {
    __shared__ __align__(16) float vs[2][8][HALF];   // double-buffered row vals
    const int t  = threadIdx.x;
    const int j  = t & 127;                // owned output column
    const int h  = t >> 7;                 // row half: rows h*4 .. h*4+3
    const int k  = 2 + (blockIdx.x >> 4);  // 30 k-values x 16 blocks = 480
    const int r0 = (blockIdx.x & 15) << 3; // 8 residues per block

    float acc[4];
    #pragma unroll
    for (int rr = 0; rr < 4; ++rr)
        acc[rr] = P[(128 + r0 + h * 4 + rr) * HALF + j];

    int p = 0;
    for (int d = 7; d < 13; ++d) {
        if ((k >> (d - 6)) == 0) break;              // block-uniform
        const float* __restrict__ Qm = QT + (((k >> (d - 7)) & 1) ? NMAT : 0);
        #pragma unroll
        for (int rr = 0; rr < 4; ++rr) vs[p][h * 4 + rr][j] = acc[rr];
        __syncthreads();                             // other buffer still live

        float nacc[4] = {0.f, 0.f, 0.f, 0.f};
        #pragma unroll 4
        for (int cc = 0; cc < 128; cc += 4) {
            float q0 = Qm[(cc + 0) * HALF + j];      // coalesced global dword
            float q1 = Qm[(cc + 1) * HALF + j];
            float q2 = Qm[(cc + 2) * HALF + j];
            float q3 = Qm[(cc + 3) * HALF + j];
            #pragma unroll
            for (int rr = 0; rr < 4; ++rr) {
                float4 v4 = *(const float4*)&vs[p][h * 4 + rr][cc];  // broadcast
                nacc[rr] = fmaf(v4.x, q0,
                           fmaf(v4.y, q1,
                           fmaf(v4.z, q2,
                           fmaf(v4.w, q3, nacc[rr]))));
            }
        }
        #pragma unroll
        for (int rr = 0; rr < 4; ++rr) acc[rr] = nacc[rr];
        p ^= 1;                                      // next step: other buffer
    }

    #pragma unroll
    for (int rr = 0; rr < 4; ++rr)
        P[((k << 7) | (r0 + h * 4 + rr)) * HALF + j] = acc[rr];
}

// ---------------------------------------------------------------------------
// K3: emit [B,S,256] = content ++ pos.  ROUND-2 VERIFIED FORM (NT stores).
// ---------------------------------------------------------------------------
__global__ __launch_bounds__(256) void emit_out(const int* __restrict__ tt,
                                                const int* __restrict__ tv,
                                                const int* __restrict__ np,
                                                const float* __restrict__ P,
                                                const float* __restrict__ emb,
                                                float* __restrict__ out) {
    const int i  = (blockIdx.x << 2) + (threadIdx.x >> 6);
    const int jj = (threadIdx.x & 63) << 2;
    const int ty = tt[i];
    const int v  = tv[i];
    f4 val;
    if (jj < 128) {
        if (ty == 0)      val = *(const f4*)&emb[jj];
        else if (ty == 1) val = *(const f4*)&emb[(v + 1) * HALF + jj];
        else if (ty == 2) val = *(const f4*)&emb[(v + 5) * HALF + jj];
        else if (ty == 4) {
            int vc = v < 0 ? 0 : (v > 4095 ? 4095 : v);
            val = *(const f4*)&P[vc * HALF + jj];
        } else if (v == -1) val = *(const f4*)&emb[10 * HALF + jj];
        else { f4 z = {0.f, 0.f, 0.f, 0.f}; val = z; }
    } else {
        const int p = np[i];
        val = *(const f4*)&P[p * HALF + (jj - 128)];
    }
    __builtin_nontemporal_store(val, (f4*)&out[i * 256 + jj]);
}

extern "C" void kernel_launch(void* const* d_in, const int* in_sizes, int n_in,
                              void* d_out, int out_size, void* d_ws, size_t ws_size,
                              hipStream_t stream) {
    const int*   token_types = (const int*)  d_in[0];
    const int*   token_vals  = (const int*)  d_in[1];
    const int*   node_pos    = (const int*)  d_in[2];
    const float* prim        = (const float*)d_in[3];
    const float* ident       = (const float*)d_in[4];
    const float* emb         = (const float*)d_in[5];
    float* out = (float*)d_out;

    // workspace: QT[2][128][128] at 0 | P[4096][128] at 262144.
    // K1's ping-pong W buffers live in the first 256 KB of the P region
    // (P is written only after K1 completes).  Barrier counter after P.
    float* QT  = (float*)d_ws;
    float* P   = (float*)((char*)d_ws + 262144);
    float* W0  = (float*)((char*)d_ws + 262144);
    float* W1  = (float*)((char*)d_ws + 262144 + 131072);
    int*   bar = (int*)  ((char*)d_ws + 2359296);

    hipMemsetAsync(bar, 0, 64, stream);              // graph-capturable
    k1_persist <<<16,  256, 0, stream>>>(prim, W0, W1, QT, bar);
    path_base  <<<64,  256, 0, stream>>>(QT, ident, P);     // rows [0,256)
    path_upper <<<480, 256, 0, stream>>>(QT, P);            // rows [256,4096)
    emit_out   <<<NTOK / 4, 256, 0, stream>>>(token_types, token_vals, node_pos,
                                              P, emb, out);
}

// Round 12
// 266.445 us; speedup vs baseline: 1.0709x; 1.0709x over previous
//
#include <hip/hip_runtime.h>

#define HALF 128
#define NMAT 16384   // 128*128
#define NTOK 131072  // 32*4096

typedef float f4 __attribute__((ext_vector_type(4)));

// N[r][c] for N = I + A/2, A = tril(X) - tril(X)^T  (identical math/order to
// the verified kernels' reg-init).
__device__ __forceinline__ float nval(const float* __restrict__ X, int r, int c) {
    int mx = r > c ? r : c;
    int mn = r ^ c ^ mx;
    float x = X[mx * HALF + mn];
    return (r == c) ? 1.0f : (r > c ? 0.5f * x : -0.5f * x);
}

// ---------------------------------------------------------------------------
// K1 (round-9 VERIFIED FORM, 266.6 us total): one kernel per GJ block-step
// (8 dispatches).  Each of the 16 blocks (2 matrices x 8 row-groups)
// redundantly runs the 16x16 shuffle-GJ and builds RB = Dinv*R in its own
// LDS.  Ping-pong W buffers: step s reads Win, writes Wout (disjoint) ->
// race-free.  Step 0 reads N from prim; step 7 writes QT = 2*W - I.
// K1-chain ledger (all alternatives measured): 16 dispatches = 88us (r8);
// 8 dispatches = 38us (r9, BEST); 4 fused 2-step = +4.5us (r10, serial work
// doubled); 1 persistent + 7 soft barriers = +18.7us (r11, device-scope
// atomic barriers cost MORE than dispatch boundaries under graph replay).
// ---------------------------------------------------------------------------
template<bool FIRST, bool LAST>
__global__ __launch_bounds__(256) void k1_step(const float* __restrict__ prim,
                                               const float* __restrict__ Win,
                                               float* __restrict__ Wout,
                                               int S) {
    __shared__ __align__(16) float Rs[16][132];   // R = pre-step W[K,:]
    __shared__ float Dc[16][17];                  // Dc[a][b] = Dinv[b][a]
    __shared__ __align__(16) float RBs[16][132];  // RB[m][c] (Dinv in panel cols)
    __shared__ float Cs[16][17];                  // own-rows C-slice

    const int blk = blockIdx.x;
    const int b   = blk >> 3;            // matrix
    const int rg  = blk & 7;             // row-group: rows r0..r0+15
    const int r0  = rg << 4;
    const int t   = threadIdx.x;
    const int k0  = S << 4;
    const float* __restrict__ X  = prim + b * NMAT;
    const float* __restrict__ Wi = Win  + b * NMAT;
    float*       __restrict__ Wo = Wout + b * NMAT;

    {   // stage R: row j = t>>4, cols 8*(t&15)..+8
        const int j  = t >> 4;
        const int c0 = (t & 15) << 3;
        if (FIRST) {
            #pragma unroll
            for (int u = 0; u < 8; ++u) Rs[j][c0 + u] = nval(X, k0 + j, c0 + u);
        } else {
            float4 a  = *(const float4*)&Wi[(k0 + j) * HALF + c0];
            float4 b2 = *(const float4*)&Wi[(k0 + j) * HALF + c0 + 4];
            *(float4*)&Rs[j][c0]     = a;
            *(float4*)&Rs[j][c0 + 4] = b2;
        }
    }
    {   // stage C-slice: rows r0..r0+16, cols k0..k0+16 (pre-step values)
        const int rr = t >> 4, m = t & 15;
        Cs[rr][m] = FIRST ? nval(X, r0 + rr, k0 + m)
                          : Wi[(r0 + rr) * HALF + k0 + m];
    }
    __syncthreads();

    if (t < 64) {   // wave 0: shuffle-GJ invert D (verbatim)
        const int cp = t & 15, q4 = t >> 4;
        float dd[4];
        #pragma unroll
        for (int i = 0; i < 4; ++i) dd[i] = Rs[q4 * 4 + i][k0 + cp];
        #pragma unroll
        for (int k = 0; k < 16; ++k) {
            float cv[4];
            #pragma unroll
            for (int i = 0; i < 4; ++i) cv[i] = __shfl(dd[i], (q4 << 4) | k);
            float rv   = __shfl(dd[k & 3], ((k >> 2) << 4) | cp);
            float dkk  = __shfl(rv, k);
            float dinv = 1.0f / dkk;
            float sv   = rv * dinv;
            bool  own  = (cp == k);
            float rf   = own ? dinv : sv;
            #pragma unroll
            for (int i = 0; i < 4; ++i)
                dd[i] = own ? (-dd[i] * dinv) : fmaf(-cv[i], sv, dd[i]);
            dd[k & 3] = (q4 == (k >> 2)) ? rf : dd[k & 3];
        }
        #pragma unroll
        for (int i = 0; i < 4; ++i) Dc[cp][q4 * 4 + i] = dd[i];
    }
    __syncthreads();

    {   // RB[m][c] in LDS: m = t>>4, cols 8*(t&15)..+8; j ascending (verbatim)
        const int m  = t >> 4;
        const int c0 = (t & 15) << 3;
        if (c0 == k0 || c0 == k0 + 8) {
            #pragma unroll
            for (int u = 0; u < 8; ++u) RBs[m][c0 + u] = Dc[c0 + u - k0][m];
        } else {
            float acc[8] = {0.f,0.f,0.f,0.f,0.f,0.f,0.f,0.f};
            #pragma unroll
            for (int j = 0; j < 16; ++j) {
                float dj = Dc[j][m];
                #pragma unroll
                for (int u = 0; u < 8; ++u)
                    acc[u] = fmaf(dj, Rs[j][c0 + u], acc[u]);
            }
            *(float4*)&RBs[m][c0]     = make_float4(acc[0], acc[1], acc[2], acc[3]);
            *(float4*)&RBs[m][c0 + 4] = make_float4(acc[4], acc[5], acc[6], acc[7]);
        }
    }
    __syncthreads();

    {   // update own 16 rows, write to Wout (disjoint -> race-free)
        const int rr = t >> 4;
        const int r  = r0 + rr;
        const int c0 = (t & 15) << 3;
        float w[8];

        if (rg == S) {                       // rows K: W[K,:] = RB
            #pragma unroll
            for (int u = 0; u < 8; ++u) w[u] = RBs[rr][c0 + u];
        } else {
            const bool pan = (c0 == k0) || (c0 == k0 + 8);
            if (pan) {
                #pragma unroll
                for (int u = 0; u < 8; ++u) w[u] = 0.0f;
            } else if (FIRST) {
                #pragma unroll
                for (int u = 0; u < 8; ++u) w[u] = nval(X, r, c0 + u);
            } else {
                float4 a  = *(const float4*)&Wi[r * HALF + c0];
                float4 b2 = *(const float4*)&Wi[r * HALF + c0 + 4];
                w[0]=a.x; w[1]=a.y; w[2]=a.z; w[3]=a.w;
                w[4]=b2.x; w[5]=b2.y; w[6]=b2.z; w[7]=b2.w;
            }
            #pragma unroll
            for (int m = 0; m < 16; ++m) {   // m ascending (verbatim)
                float cm = Cs[rr][m];
                #pragma unroll
                for (int u = 0; u < 8; ++u)
                    w[u] = fmaf(-cm, RBs[m][c0 + u], w[u]);
            }
        }

        if (LAST) {
            #pragma unroll
            for (int u = 0; u < 8; ++u)
                w[u] = 2.0f * w[u] - ((r == c0 + u) ? 1.0f : 0.0f);
        }
        *(float4*)&Wo[r * HALF + c0]     = make_float4(w[0], w[1], w[2], w[3]);
        *(float4*)&Wo[r * HALF + c0 + 4] = make_float4(w[4], w[5], w[6], w[7]);
    }
}

// ---------------------------------------------------------------------------
// K2a: rows [0,256) from identity, steps d=0..6.  ROUND-2 VERIFIED FORM.
// ---------------------------------------------------------------------------
__global__ __launch_bounds__(256) void path_base(const float* __restrict__ QT,
                                                 const float* __restrict__ ident,
                                                 float* __restrict__ P) {
    __shared__ __align__(16) float vs[2][4][HALF];
    const int t    = threadIdx.x;
    const int rg   = t >> 6;                 // row in block (0..3), one wave each
    const int jj   = (t & 63) << 1;          // 2-col chunk
    const int v    = (blockIdx.x << 2) + rg;
    const int vmax = (blockIdx.x << 2) + 3;

    float2 cv = *(const float2*)&ident[jj];
    *(float2*)&vs[0][rg][jj] = cv;
    __syncthreads();

    int cur = 0;
    for (int d = 0; d < 8; ++d) {
        if ((vmax >> (d + 1)) == 0) break;           // block-uniform
        const bool valid = (v >> (d + 1)) > 0;
        const float* __restrict__ Qm = QT + (((v >> d) & 1) ? NMAT : 0);
        float2 acc = make_float2(0.f, 0.f);
        #pragma unroll 4
        for (int cc = 0; cc < 128; cc += 4) {
            float4 v4 = *(const float4*)&vs[cur][rg][cc];
            float2 q0 = *(const float2*)&Qm[(cc+0)*HALF + jj];
            float2 q1 = *(const float2*)&Qm[(cc+1)*HALF + jj];
            float2 q2 = *(const float2*)&Qm[(cc+2)*HALF + jj];
            float2 q3 = *(const float2*)&Qm[(cc+3)*HALF + jj];
            acc.x = fmaf(v4.x,q0.x, fmaf(v4.y,q1.x, fmaf(v4.z,q2.x, fmaf(v4.w,q3.x, acc.x))));
            acc.y = fmaf(v4.x,q0.y, fmaf(v4.y,q1.y, fmaf(v4.z,q2.y, fmaf(v4.w,q3.y, acc.y))));
        }
        if (valid) cv = acc;
        *(float2*)&vs[cur ^ 1][rg][jj] = cv;
        __syncthreads();
        cur ^= 1;
    }
    *(float2*)&P[v * HALF + jj] = cv;
}

// ---------------------------------------------------------------------------
// K2b: rows [256,4096), k-grouped, column-parallel, 256 threads.
// ROUND-4 VERIFIED FORM.
// ---------------------------------------------------------------------------
__global__ __launch_bounds__(256) void path_upper(const float* __restrict__ QT,
                                                  float* __restrict__ P) {
    __shared__ __align__(16) float vs[2][8][HALF];   // double-buffered row vals
    const int t  = threadIdx.x;
    const int j  = t & 127;                // owned output column
    const int h  = t >> 7;                 // row half: rows h*4 .. h*4+3
    const int k  = 2 + (blockIdx.x >> 4);  // 30 k-values x 16 blocks = 480
    const int r0 = (blockIdx.x & 15) << 3; // 8 residues per block

    float acc[4];
    #pragma unroll
    for (int rr = 0; rr < 4; ++rr)
        acc[rr] = P[(128 + r0 + h * 4 + rr) * HALF + j];

    int p = 0;
    for (int d = 7; d < 13; ++d) {
        if ((k >> (d - 6)) == 0) break;              // block-uniform
        const float* __restrict__ Qm = QT + (((k >> (d - 7)) & 1) ? NMAT : 0);
        #pragma unroll
        for (int rr = 0; rr < 4; ++rr) vs[p][h * 4 + rr][j] = acc[rr];
        __syncthreads();                             // other buffer still live

        float nacc[4] = {0.f, 0.f, 0.f, 0.f};
        #pragma unroll 4
        for (int cc = 0; cc < 128; cc += 4) {
            float q0 = Qm[(cc + 0) * HALF + j];      // coalesced global dword
            float q1 = Qm[(cc + 1) * HALF + j];
            float q2 = Qm[(cc + 2) * HALF + j];
            float q3 = Qm[(cc + 3) * HALF + j];
            #pragma unroll
            for (int rr = 0; rr < 4; ++rr) {
                float4 v4 = *(const float4*)&vs[p][h * 4 + rr][cc];  // broadcast
                nacc[rr] = fmaf(v4.x, q0,
                           fmaf(v4.y, q1,
                           fmaf(v4.z, q2,
                           fmaf(v4.w, q3, nacc[rr]))));
            }
        }
        #pragma unroll
        for (int rr = 0; rr < 4; ++rr) acc[rr] = nacc[rr];
        p ^= 1;                                      // next step: other buffer
    }

    #pragma unroll
    for (int rr = 0; rr < 4; ++rr)
        P[((k << 7) | (r0 + h * 4 + rr)) * HALF + j] = acc[rr];
}

// ---------------------------------------------------------------------------
// K3: emit [B,S,256] = content ++ pos.  ROUND-2 VERIFIED FORM (NT stores;
// at the ~21 us HBM write floor).
// ---------------------------------------------------------------------------
__global__ __launch_bounds__(256) void emit_out(const int* __restrict__ tt,
                                                const int* __restrict__ tv,
                                                const int* __restrict__ np,
                                                const float* __restrict__ P,
                                                const float* __restrict__ emb,
                                                float* __restrict__ out) {
    const int i  = (blockIdx.x << 2) + (threadIdx.x >> 6);
    const int jj = (threadIdx.x & 63) << 2;
    const int ty = tt[i];
    const int v  = tv[i];
    f4 val;
    if (jj < 128) {
        if (ty == 0)      val = *(const f4*)&emb[jj];
        else if (ty == 1) val = *(const f4*)&emb[(v + 1) * HALF + jj];
        else if (ty == 2) val = *(const f4*)&emb[(v + 5) * HALF + jj];
        else if (ty == 4) {
            int vc = v < 0 ? 0 : (v > 4095 ? 4095 : v);
            val = *(const f4*)&P[vc * HALF + jj];
        } else if (v == -1) val = *(const f4*)&emb[10 * HALF + jj];
        else { f4 z = {0.f, 0.f, 0.f, 0.f}; val = z; }
    } else {
        const int p = np[i];
        val = *(const f4*)&P[p * HALF + (jj - 128)];
    }
    __builtin_nontemporal_store(val, (f4*)&out[i * 256 + jj]);
}

extern "C" void kernel_launch(void* const* d_in, const int* in_sizes, int n_in,
                              void* d_out, int out_size, void* d_ws, size_t ws_size,
                              hipStream_t stream) {
    const int*   token_types = (const int*)  d_in[0];
    const int*   token_vals  = (const int*)  d_in[1];
    const int*   node_pos    = (const int*)  d_in[2];
    const float* prim        = (const float*)d_in[3];
    const float* ident       = (const float*)d_in[4];
    const float* emb         = (const float*)d_in[5];
    float* out = (float*)d_out;

    // workspace: QT[2][128][128] at 0 | P[4096][128] at 262144.
    // K1's ping-pong W buffers live in the first 256 KB of the P region --
    // P is written only after K1 completes (stream-ordered), so no conflict.
    float* QT = (float*)d_ws;
    float* P  = (float*)((char*)d_ws + 262144);
    float* W0 = (float*)((char*)d_ws + 262144);
    float* W1 = (float*)((char*)d_ws + 262144 + 131072);

    k1_step<true,  false><<<16, 256, 0, stream>>>(prim, W0, W0, 0);  // N -> W0
    k1_step<false, false><<<16, 256, 0, stream>>>(prim, W0, W1, 1);
    k1_step<false, false><<<16, 256, 0, stream>>>(prim, W1, W0, 2);
    k1_step<false, false><<<16, 256, 0, stream>>>(prim, W0, W1, 3);
    k1_step<false, false><<<16, 256, 0, stream>>>(prim, W1, W0, 4);
    k1_step<false, false><<<16, 256, 0, stream>>>(prim, W0, W1, 5);
    k1_step<false, false><<<16, 256, 0, stream>>>(prim, W1, W0, 6);
    k1_step<false, true ><<<16, 256, 0, stream>>>(prim, W0, QT, 7);  // 2W - I

    path_base  <<<64,  256, 0, stream>>>(QT, ident, P);     // rows [0,256)
    path_upper <<<480, 256, 0, stream>>>(QT, P);            // rows [256,4096)
    emit_out   <<<NTOK / 4, 256, 0, stream>>>(token_types, token_vals, node_pos,
                                              P, emb, out);
}